// Round 5
// baseline (1403.689 us; speedup 1.0000x reference)
//
#include <hip/hip_runtime.h>

// 6-level 2D DB4 wavelet (forward -> soft threshold -> inverse), N=4096 fp32.
// R7: R6 design with two fixes. ONE plain persistent kernel (no coop launch --
// R5 showed ~150us cost; no cg::grid.sync -- R4 showed ~165us/sync at 1024 WGs).
// 12 phases (fwd 0..5 with thr folded into fwd5, inv 5..0) driven by a
// dispatch-order-safe work queue:
//   - per-phase ticket atomic: running blocks dynamically claim tile chunks;
//     blocks that start late find tickets exhausted and fall through (G16-safe,
//     deadlock-free under ANY residency -- gates wait on WORK, never on blocks).
//   - per-phase done counter (tiles completed), incremented with __threadfence
//     (release) after __syncthreads; gate = acquire-poll until
//     done[p-1]==Ntiles[p-1] (same coherence pattern verified in R5).
//   - tiny init kernel zeroes the 256-uint counter region (ws is re-poisoned).
// Fixes vs R6 (which never compiled):
//   1. s_sleep needs an IMMEDIATE operand (ImmArg intrinsic) -- R6 passed a
//      runtime variable => compile error => "container failed twice".
//   2. chunk size cs=4 only when Np>=4096 (R6's Np>=256 threshold would have
//      serialized 1024-tile phases onto 256 blocks: 4x critical path).
// 2 plain launches total.
//
// Tile bodies identical to R3/R5 (verified): fwd 32x32-out tiles, inv 64x64-out
// tiles, register sliding windows, no parity divergence, float4 I/O.
// LDS union 40320 B -> 4 blocks/CU -> 1024 blocks fill the machine.
//
// d_out layout: [0 .. 16777216) reconstruction, [16777216 .. 33554432) flat coeffs.
// Flat per level: row i = [hh_i | hl_i | lh_i], row stride 3*sc; final thr(approx)
// (64x64) at the tail.
// ws layout (floats): A1..A6 [0 .. 5591040) | P0 (4194304) | P1 (4194304) |
// counter region (256 uints) at float offset 14680064.

#define NBLK 1024

__device__ __forceinline__ float thrf(float t, float alpha, float bp, float bm) {
    float s1 = 1.0f / (1.0f + __expf(-alpha * (t - bp)));
    float s2 = 1.0f / (1.0f + __expf( alpha * (t + bm)));
    return t * (s1 + s2);
}

__device__ __forceinline__ void load_filt(const float* __restrict__ filt,
                                          float (&h)[8], float (&w)[8]) {
#pragma unroll
    for (int k = 0; k < 8; ++k) h[k] = filt[k];
#pragma unroll
    for (int k = 0; k < 8; ++k) w[k] = (k & 1) ? -h[7 - k] : h[7 - k];
}

struct SMemF {
    float xs[70][72];   // 20160 B
    float Ds[70][36];   // 10080 B
    float As[70][36];   // 10080 B
};
struct SMemI {
    float hh[36][36], hl[36][36], lh[36][36], as0[36][36]; // 20736 B
    float Hs[64][36], Ls[64][36];                          // 18432 B
};
union SMem {
    SMemF f;  // 40320 B
    SMemI i;  // 39168 B
};

// Forward tile: X (s x s) -> thresholded hh|hl|lh into flat (stride 3*sh)
// + ll into All (stride sh; thresholded too when thr_ll).
__device__ __forceinline__ void fwd_tile(
    SMemF& sm, const float* __restrict__ X, int s, int sh,
    float* __restrict__ flat, float* __restrict__ All, bool thr_ll,
    const float (&hr)[8], const float (&wr)[8],
    const float (&hc)[8], const float (&wc)[8],
    float alpha, float bp, float bm, int i0, int j0, int tid) {
    const int smk = s - 1;
    // stage 1: global -> LDS, float4 chunks (col base shifted to -8 for alignment)
    for (int idx = tid; idx < 70 * 18; idx += 256) {
        int rr = idx / 18, c = idx - rr * 18;
        int gr = (2 * i0 - 7 + rr) & smk;
        int gc = (2 * j0 - 8 + 4 * c) & smk;
        *(float4*)&sm.xs[rr][4 * c] = *(const float4*)&X[(size_t)gr * s + gc];
    }
    __syncthreads();
    // stage 2: row filter, 4 outputs per item from one 16-float window.
    for (int idx = tid; idx < 70 * 8; idx += 256) {
        int rr = idx >> 3, q = idx & 7;
        const float4* xr = (const float4*)&sm.xs[rr][8 * q];
        float wv[16];
#pragma unroll
        for (int m = 0; m < 4; ++m) {
            float4 t = xr[m];
            wv[4 * m + 0] = t.x; wv[4 * m + 1] = t.y;
            wv[4 * m + 2] = t.z; wv[4 * m + 3] = t.w;
        }
        float d[4], a[4];
#pragma unroll
        for (int e = 0; e < 4; ++e) {
            float dd = 0.f, aa = 0.f;
#pragma unroll
            for (int u = 0; u < 8; ++u) {
                float v = wv[2 * e + 1 + u];
                dd += wr[7 - u] * v;
                aa += hr[7 - u] * v;
            }
            d[e] = dd; a[e] = aa;
        }
        *(float4*)&sm.Ds[rr][4 * q] = make_float4(d[0], d[1], d[2], d[3]);
        *(float4*)&sm.As[rr][4 * q] = make_float4(a[0], a[1], a[2], a[3]);
    }
    __syncthreads();
    // stage 3: col filter + threshold + store; 4 outputs from a 14-row window.
    {
        const int j = tid & 31, iq = tid >> 5;
        float Dw[14], Aw[14];
#pragma unroll
        for (int t = 0; t < 14; ++t) {
            Dw[t] = sm.Ds[8 * iq + t][j];
            Aw[t] = sm.As[8 * iq + t][j];
        }
#pragma unroll
        for (int e = 0; e < 4; ++e) {
            float hh = 0.f, hl = 0.f, lh = 0.f, ll = 0.f;
#pragma unroll
            for (int u = 0; u < 8; ++u) {
                float dv = Dw[2 * e + u], av = Aw[2 * e + u];
                hh += wc[7 - u] * dv;
                hl += hc[7 - u] * dv;
                lh += wc[7 - u] * av;
                ll += hc[7 - u] * av;
            }
            int row = i0 + 4 * iq + e;
            size_t ro = (size_t)row * (3 * sh) + (j0 + j);
            flat[ro]          = thrf(hh, alpha, bp, bm);
            flat[ro + sh]     = thrf(hl, alpha, bp, bm);
            flat[ro + 2 * sh] = thrf(lh, alpha, bp, bm);
            All[(size_t)row * sh + (j0 + j)] =
                thr_ll ? thrf(ll, alpha, bp, bm) : ll;
        }
    }
}

// Inverse tile: hh|hl|lh (stride 3*sc) + a (stride astride) -> 64x64 out tile.
__device__ __forceinline__ void inv_tile(
    SMemI& sm, const float* __restrict__ flatl, const float* __restrict__ a,
    int astride, int sc, float* __restrict__ outp, int ostride,
    const float (&hr)[8], const float (&wr)[8],
    const float (&hc)[8], const float (&wc)[8],
    int i0, int m0, int tid) {
    const int mm = sc - 1;
    const int r0 = i0 >> 1, c0 = m0 >> 1;
    const int ds = 3 * sc;
    // stage 1: load 36x36 tiles of all four coefficient arrays as float4 chunks.
    for (int idx = tid; idx < 4 * 324; idx += 256) {
        int aid = idx / 324, rem = idx - aid * 324;
        int rr = rem / 9, c = rem - rr * 9;
        int gr = (r0 + rr) & mm;
        int gc = (c0 + 4 * c) & mm;
        if (aid == 0)
            *(float4*)&sm.hh[rr][4 * c] = *(const float4*)&flatl[(size_t)gr * ds + gc];
        else if (aid == 1)
            *(float4*)&sm.hl[rr][4 * c] = *(const float4*)&flatl[(size_t)gr * ds + sc + gc];
        else if (aid == 2)
            *(float4*)&sm.lh[rr][4 * c] = *(const float4*)&flatl[(size_t)gr * ds + 2 * sc + gc];
        else
            *(float4*)&sm.as0[rr][4 * c] = *(const float4*)&a[(size_t)gr * astride + gc];
    }
    __syncthreads();
    // stage 2: col inverse, 4 rows per item from a 6-row window (no divergence).
    for (int idx = tid; idx < 16 * 36; idx += 256) {
        int q = idx / 36, jj = idx - q * 36;
        float hv[6], lv[6], gv[6], av[6];
#pragma unroll
        for (int d = 0; d < 6; ++d) {
            int lr = 2 * q + d;
            hv[d] = sm.hh[lr][jj];
            lv[d] = sm.hl[lr][jj];
            gv[d] = sm.lh[lr][jj];
            av[d] = sm.as0[lr][jj];
        }
        float H0 = 0.f, H1 = 0.f, H2 = 0.f, H3 = 0.f;
        float L0 = 0.f, L1 = 0.f, L2 = 0.f, L3 = 0.f;
#pragma unroll
        for (int t = 0; t < 4; ++t) {
            float we = wc[2 * t], he = hc[2 * t];
            float wo = wc[2 * t + 1], ho = hc[2 * t + 1];
            H0 += we * hv[t]     + he * lv[t];
            H1 += wo * hv[t + 1] + ho * lv[t + 1];
            H2 += we * hv[t + 1] + he * lv[t + 1];
            H3 += wo * hv[t + 2] + ho * lv[t + 2];
            L0 += we * gv[t]     + he * av[t];
            L1 += wo * gv[t + 1] + ho * av[t + 1];
            L2 += we * gv[t + 1] + he * av[t + 1];
            L3 += wo * gv[t + 2] + ho * av[t + 2];
        }
        sm.Hs[4 * q + 0][jj] = H0; sm.Hs[4 * q + 1][jj] = H1;
        sm.Hs[4 * q + 2][jj] = H2; sm.Hs[4 * q + 3][jj] = H3;
        sm.Ls[4 * q + 0][jj] = L0; sm.Ls[4 * q + 1][jj] = L1;
        sm.Ls[4 * q + 2][jj] = L2; sm.Ls[4 * q + 3][jj] = L3;
    }
    __syncthreads();
    // stage 3: row inverse, 4 outputs per item from a 6-col window, float4 store.
    for (int idx = tid; idx < 64 * 16; idx += 256) {
        int i = idx >> 4, p = idx & 15;
        const float2* hp = (const float2*)&sm.Hs[i][2 * p];
        const float2* lp = (const float2*)&sm.Ls[i][2 * p];
        float2 hA = hp[0], hB = hp[1], hC = hp[2];
        float2 lA = lp[0], lB = lp[1], lC = lp[2];
        float Hw[6] = {hA.x, hA.y, hB.x, hB.y, hC.x, hC.y};
        float Lw[6] = {lA.x, lA.y, lB.x, lB.y, lC.x, lC.y};
        float o0 = 0.f, o1 = 0.f, o2 = 0.f, o3 = 0.f;
#pragma unroll
        for (int t = 0; t < 4; ++t) {
            float we = wr[2 * t], he = hr[2 * t];
            float wo = wr[2 * t + 1], ho = hr[2 * t + 1];
            o0 += we * Hw[t]     + he * Lw[t];
            o1 += wo * Hw[t + 1] + ho * Lw[t + 1];
            o2 += we * Hw[t + 1] + he * Lw[t + 1];
            o3 += wo * Hw[t + 2] + ho * Lw[t + 2];
        }
        *(float4*)&outp[(size_t)(i0 + i) * ostride + (m0 + 4 * p)] =
            make_float4(o0, o1, o2, o3);
    }
}

// zero the ticket/done counter region (ws is re-poisoned each iteration)
__global__ void init_bar(unsigned* __restrict__ bar) {
    bar[threadIdx.x] = 0u;
}

// Counter layout: bar[p*16 + 0] = ticket (chunks claimed), bar[p*16 + 8] = done
// (tiles completed), p = 0..11.
__global__ __launch_bounds__(256) void persist(
    const float* __restrict__ x, const float* __restrict__ scal,
    const float* __restrict__ ap, const float* __restrict__ bpp,
    const float* __restrict__ bmp, float* __restrict__ out,
    float* __restrict__ ws, unsigned* __restrict__ bar) {
    __shared__ SMem smem;
    __shared__ int curt;
    const int tid = threadIdx.x;
    const float alpha = *ap, bp = *bpp, bm = *bmp;
    const int N = 4096;
    float* flat = out + 16777216;
    const size_t Aoff[7]    = {0, 0, 4194304, 5242880, 5505024, 5570560, 5586944};
    const size_t flatOff[6] = {0, 12582912, 15728640, 16515072, 16711680, 16760832};
    const size_t finalOff = 16773120;
    float* P0 = ws + 5591040;
    float* P1 = ws + 5591040 + 4194304;

    const float* a_in = flat + finalOff;

    for (int p = 0; p < 12; ++p) {
        const int lev = (p < 6) ? p : 11 - p;
        const int nt  = N >> (lev + 6);      // tiles per side (same fwd/inv)
        const int Np  = nt * nt;

        // ---- gate: wait for ALL tiles of phase p-1 (work-based, deadlock-free)
        if (p > 0) {
            const int plev = (p - 1 < 6) ? (p - 1) : (12 - p);
            const int pnt  = N >> (plev + 6);
            const unsigned tgt = (unsigned)(pnt * pnt);
            if (tid == 0) {
                while (__hip_atomic_load(&bar[(p - 1) * 16 + 8], __ATOMIC_ACQUIRE,
                                         __HIP_MEMORY_SCOPE_AGENT) < tgt) {
                    __builtin_amdgcn_s_sleep(4);  // immediate operand (ImmArg)
                }
            }
            __syncthreads();
        }

        float hr[8], wr[8], hc[8], wc[8];
        load_filt(scal + lev * 8, hr, wr);
        load_filt(scal + (lev + 1) * 8, hc, wc);

        const int cs = (Np >= 4096) ? 4 : 1;  // tiles per ticket (critical-path safe)
        const int Nc = Np / cs;
        unsigned cnt = 0;

        if (p < 6) {
            const int s = N >> lev, sh = s >> 1;
            const float* src = (lev == 0) ? x : (ws + Aoff[lev]);
            float* All = (lev < 5) ? (ws + Aoff[lev + 1]) : (flat + finalOff);
            for (;;) {
                __syncthreads();
                if (tid == 0) curt = (int)atomicAdd(&bar[p * 16], 1u);
                __syncthreads();
                const int ch = curt;
                if (ch >= Nc) break;
#pragma unroll 1
                for (int e = 0; e < cs; ++e) {
                    if (e) __syncthreads();
                    const int t = ch * cs + e;
                    fwd_tile(smem.f, src, s, sh, flat + flatOff[lev], All, lev == 5,
                             hr, wr, hc, wc, alpha, bp, bm,
                             (t / nt) * 32, (t % nt) * 32, tid);
                }
                cnt += cs;
            }
        } else {
            const int sc = N >> (lev + 1), r = 2 * sc;
            float* outp = (lev == 0) ? out : ((lev & 1) ? P1 : P0);
            for (;;) {
                __syncthreads();
                if (tid == 0) curt = (int)atomicAdd(&bar[p * 16], 1u);
                __syncthreads();
                const int ch = curt;
                if (ch >= Nc) break;
#pragma unroll 1
                for (int e = 0; e < cs; ++e) {
                    if (e) __syncthreads();
                    const int t = ch * cs + e;
                    inv_tile(smem.i, flat + flatOff[lev], a_in, sc, sc, outp, r,
                             hr, wr, hc, wc, (t / nt) * 64, (t % nt) * 64, tid);
                }
                cnt += cs;
            }
            a_in = outp;  // uniform across block
        }

        // ---- signal completion of our tiles (release: fence then add)
        __syncthreads();
        if (tid == 0 && cnt) {
            __threadfence();
            atomicAdd(&bar[p * 16 + 8], cnt);
        }
    }
}

extern "C" void kernel_launch(void* const* d_in, const int* in_sizes, int n_in,
                              void* d_out, int out_size, void* d_ws, size_t ws_size,
                              hipStream_t stream) {
    const float* x    = (const float*)d_in[0];
    const float* scal = (const float*)d_in[1];  // 12 x 8
    const float* ap   = (const float*)d_in[2];
    const float* bp   = (const float*)d_in[3];
    const float* bm   = (const float*)d_in[4];
    float* out = (float*)d_out;
    float* ws  = (float*)d_ws;

    unsigned* bar = (unsigned*)(ws + 14680064);  // past all live ws data

    init_bar<<<dim3(1), dim3(256), 0, stream>>>(bar);
    persist<<<dim3(NBLK), dim3(256), 0, stream>>>(x, scal, ap, bp, bm, out, ws, bar);
}

// Round 6
// 321.188 us; speedup vs baseline: 4.3703x; 4.3703x over previous
//
#include <hip/hip_runtime.h>

// 6-level 2D DB4 wavelet (forward -> soft threshold -> inverse), N=4096 fp32.
// R8: R5 structure with the coop launch replaced by a PLAIN launch (R5 measured
// coop-launch overhead ~150us; R4/R7 showed grid-wide sync at >=1024 WGs costs
// 100-165us/phase -- per-block cross-XCD L2 writeback/invalidate). 7 plain
// launches:
//   fwd0, fwd1, fwd2(+bar reset), core_small(64 WGs: fwd3..5 + thr + inv5..3),
//   inv2, inv1, inv0.
// core_small uses the R7-proven work-based gate (per-phase done counter; wait on
// WORK not blocks -> deadlock-free under any residency, G16-safe), with relaxed
// polling + one acquire fence (no per-iteration invalidate spam). At 64 WGs the
// per-block release fence cost is small (8 blocks/XCD).
//
// Tile bodies identical to R3/R5/R7 (verified): fwd 32x32-out tiles, inv
// 64x64-out tiles, register sliding windows, no parity divergence, float4 I/O.
//
// d_out layout: [0 .. 16777216) reconstruction, [16777216 .. 33554432) flat coeffs.
// Flat per level: row i = [hh_i | hl_i | lh_i], row stride 3*sc; final thr(approx)
// (64x64) at the tail.
// ws layout (floats): A1..A6 [0 .. 5591040) | P0 (4194304) | P1 (4194304) |
// done-counter region at float offset 14680064 (8 slots, 128B apart).

#define CORE_WGS 64

__device__ __forceinline__ float thrf(float t, float alpha, float bp, float bm) {
    float s1 = 1.0f / (1.0f + __expf(-alpha * (t - bp)));
    float s2 = 1.0f / (1.0f + __expf( alpha * (t + bm)));
    return t * (s1 + s2);
}

__device__ __forceinline__ void load_filt(const float* __restrict__ filt,
                                          float (&h)[8], float (&w)[8]) {
#pragma unroll
    for (int k = 0; k < 8; ++k) h[k] = filt[k];
#pragma unroll
    for (int k = 0; k < 8; ++k) w[k] = (k & 1) ? -h[7 - k] : h[7 - k];
}

struct SMemF {
    float xs[70][72];   // 20160 B
    float Ds[70][36];   // 10080 B
    float As[70][36];   // 10080 B
};
struct SMemI {
    float hh[36][36], hl[36][36], lh[36][36], as0[36][36]; // 20736 B
    float Hs[64][36], Ls[64][36];                          // 18432 B
};
union SMem {
    SMemF f;  // 40320 B
    SMemI i;  // 39168 B
};

// Forward tile: X (s x s) -> thresholded hh|hl|lh into flat (stride 3*sh)
// + ll into All (stride sh; thresholded too when thr_ll).
__device__ __forceinline__ void fwd_tile(
    SMemF& sm, const float* __restrict__ X, int s, int sh,
    float* __restrict__ flat, float* __restrict__ All, bool thr_ll,
    const float (&hr)[8], const float (&wr)[8],
    const float (&hc)[8], const float (&wc)[8],
    float alpha, float bp, float bm, int i0, int j0, int tid) {
    const int smk = s - 1;
    // stage 1: global -> LDS, float4 chunks (col base shifted to -8 for alignment)
    for (int idx = tid; idx < 70 * 18; idx += 256) {
        int rr = idx / 18, c = idx - rr * 18;
        int gr = (2 * i0 - 7 + rr) & smk;
        int gc = (2 * j0 - 8 + 4 * c) & smk;
        *(float4*)&sm.xs[rr][4 * c] = *(const float4*)&X[(size_t)gr * s + gc];
    }
    __syncthreads();
    // stage 2: row filter, 4 outputs per item from one 16-float window.
    for (int idx = tid; idx < 70 * 8; idx += 256) {
        int rr = idx >> 3, q = idx & 7;
        const float4* xr = (const float4*)&sm.xs[rr][8 * q];
        float wv[16];
#pragma unroll
        for (int m = 0; m < 4; ++m) {
            float4 t = xr[m];
            wv[4 * m + 0] = t.x; wv[4 * m + 1] = t.y;
            wv[4 * m + 2] = t.z; wv[4 * m + 3] = t.w;
        }
        float d[4], a[4];
#pragma unroll
        for (int e = 0; e < 4; ++e) {
            float dd = 0.f, aa = 0.f;
#pragma unroll
            for (int u = 0; u < 8; ++u) {
                float v = wv[2 * e + 1 + u];
                dd += wr[7 - u] * v;
                aa += hr[7 - u] * v;
            }
            d[e] = dd; a[e] = aa;
        }
        *(float4*)&sm.Ds[rr][4 * q] = make_float4(d[0], d[1], d[2], d[3]);
        *(float4*)&sm.As[rr][4 * q] = make_float4(a[0], a[1], a[2], a[3]);
    }
    __syncthreads();
    // stage 3: col filter + threshold + store; 4 outputs from a 14-row window.
    {
        const int j = tid & 31, iq = tid >> 5;
        float Dw[14], Aw[14];
#pragma unroll
        for (int t = 0; t < 14; ++t) {
            Dw[t] = sm.Ds[8 * iq + t][j];
            Aw[t] = sm.As[8 * iq + t][j];
        }
#pragma unroll
        for (int e = 0; e < 4; ++e) {
            float hh = 0.f, hl = 0.f, lh = 0.f, ll = 0.f;
#pragma unroll
            for (int u = 0; u < 8; ++u) {
                float dv = Dw[2 * e + u], av = Aw[2 * e + u];
                hh += wc[7 - u] * dv;
                hl += hc[7 - u] * dv;
                lh += wc[7 - u] * av;
                ll += hc[7 - u] * av;
            }
            int row = i0 + 4 * iq + e;
            size_t ro = (size_t)row * (3 * sh) + (j0 + j);
            flat[ro]          = thrf(hh, alpha, bp, bm);
            flat[ro + sh]     = thrf(hl, alpha, bp, bm);
            flat[ro + 2 * sh] = thrf(lh, alpha, bp, bm);
            All[(size_t)row * sh + (j0 + j)] =
                thr_ll ? thrf(ll, alpha, bp, bm) : ll;
        }
    }
}

// Inverse tile: hh|hl|lh (stride 3*sc) + a (stride astride) -> 64x64 out tile.
__device__ __forceinline__ void inv_tile(
    SMemI& sm, const float* __restrict__ flatl, const float* __restrict__ a,
    int astride, int sc, float* __restrict__ outp, int ostride,
    const float (&hr)[8], const float (&wr)[8],
    const float (&hc)[8], const float (&wc)[8],
    int i0, int m0, int tid) {
    const int mm = sc - 1;
    const int r0 = i0 >> 1, c0 = m0 >> 1;
    const int ds = 3 * sc;
    // stage 1: load 36x36 tiles of all four coefficient arrays as float4 chunks.
    for (int idx = tid; idx < 4 * 324; idx += 256) {
        int aid = idx / 324, rem = idx - aid * 324;
        int rr = rem / 9, c = rem - rr * 9;
        int gr = (r0 + rr) & mm;
        int gc = (c0 + 4 * c) & mm;
        if (aid == 0)
            *(float4*)&sm.hh[rr][4 * c] = *(const float4*)&flatl[(size_t)gr * ds + gc];
        else if (aid == 1)
            *(float4*)&sm.hl[rr][4 * c] = *(const float4*)&flatl[(size_t)gr * ds + sc + gc];
        else if (aid == 2)
            *(float4*)&sm.lh[rr][4 * c] = *(const float4*)&flatl[(size_t)gr * ds + 2 * sc + gc];
        else
            *(float4*)&sm.as0[rr][4 * c] = *(const float4*)&a[(size_t)gr * astride + gc];
    }
    __syncthreads();
    // stage 2: col inverse, 4 rows per item from a 6-row window (no divergence).
    for (int idx = tid; idx < 16 * 36; idx += 256) {
        int q = idx / 36, jj = idx - q * 36;
        float hv[6], lv[6], gv[6], av[6];
#pragma unroll
        for (int d = 0; d < 6; ++d) {
            int lr = 2 * q + d;
            hv[d] = sm.hh[lr][jj];
            lv[d] = sm.hl[lr][jj];
            gv[d] = sm.lh[lr][jj];
            av[d] = sm.as0[lr][jj];
        }
        float H0 = 0.f, H1 = 0.f, H2 = 0.f, H3 = 0.f;
        float L0 = 0.f, L1 = 0.f, L2 = 0.f, L3 = 0.f;
#pragma unroll
        for (int t = 0; t < 4; ++t) {
            float we = wc[2 * t], he = hc[2 * t];
            float wo = wc[2 * t + 1], ho = hc[2 * t + 1];
            H0 += we * hv[t]     + he * lv[t];
            H1 += wo * hv[t + 1] + ho * lv[t + 1];
            H2 += we * hv[t + 1] + he * lv[t + 1];
            H3 += wo * hv[t + 2] + ho * lv[t + 2];
            L0 += we * gv[t]     + he * av[t];
            L1 += wo * gv[t + 1] + ho * av[t + 1];
            L2 += we * gv[t + 1] + he * av[t + 1];
            L3 += wo * gv[t + 2] + ho * av[t + 2];
        }
        sm.Hs[4 * q + 0][jj] = H0; sm.Hs[4 * q + 1][jj] = H1;
        sm.Hs[4 * q + 2][jj] = H2; sm.Hs[4 * q + 3][jj] = H3;
        sm.Ls[4 * q + 0][jj] = L0; sm.Ls[4 * q + 1][jj] = L1;
        sm.Ls[4 * q + 2][jj] = L2; sm.Ls[4 * q + 3][jj] = L3;
    }
    __syncthreads();
    // stage 3: row inverse, 4 outputs per item from a 6-col window, float4 store.
    for (int idx = tid; idx < 64 * 16; idx += 256) {
        int i = idx >> 4, p = idx & 15;
        const float2* hp = (const float2*)&sm.Hs[i][2 * p];
        const float2* lp = (const float2*)&sm.Ls[i][2 * p];
        float2 hA = hp[0], hB = hp[1], hC = hp[2];
        float2 lA = lp[0], lB = lp[1], lC = lp[2];
        float Hw[6] = {hA.x, hA.y, hB.x, hB.y, hC.x, hC.y};
        float Lw[6] = {lA.x, lA.y, lB.x, lB.y, lC.x, lC.y};
        float o0 = 0.f, o1 = 0.f, o2 = 0.f, o3 = 0.f;
#pragma unroll
        for (int t = 0; t < 4; ++t) {
            float we = wr[2 * t], he = hr[2 * t];
            float wo = wr[2 * t + 1], ho = hr[2 * t + 1];
            o0 += we * Hw[t]     + he * Lw[t];
            o1 += wo * Hw[t + 1] + ho * Lw[t + 1];
            o2 += we * Hw[t + 1] + he * Lw[t + 1];
            o3 += wo * Hw[t + 2] + ho * Lw[t + 2];
        }
        *(float4*)&outp[(size_t)(i0 + i) * ostride + (m0 + 4 * p)] =
            make_float4(o0, o1, o2, o3);
    }
}

// ---- standalone kernels for big levels (0..2), one tile per block ----
__global__ __launch_bounds__(256) void fwd_fused(
    const float* __restrict__ X, int s, int sh,
    float* __restrict__ flat, float* __restrict__ All,
    const float* __restrict__ filt_row, const float* __restrict__ filt_col,
    const float* __restrict__ ap, const float* __restrict__ bpp,
    const float* __restrict__ bmp, unsigned* bar_reset) {
    __shared__ SMem smem;
    float hr[8], wr[8], hc[8], wc[8];
    load_filt(filt_row, hr, wr);
    load_filt(filt_col, hc, wc);
    const float alpha = *ap, bp = *bpp, bm = *bmp;
    fwd_tile(smem.f, X, s, sh, flat, All, false, hr, wr, hc, wc,
             alpha, bp, bm, blockIdx.y * 32, blockIdx.x * 32, threadIdx.x);
    // zero the 8 done-counter slots (128B apart); fwd2 strictly precedes core
    if (bar_reset && blockIdx.x == 0 && blockIdx.y == 0 && threadIdx.x < 8)
        bar_reset[threadIdx.x * 32] = 0u;
}

__global__ __launch_bounds__(256) void inv_fused(
    const float* __restrict__ flatl, const float* __restrict__ a, int astride,
    int sc, float* __restrict__ outp, int ostride,
    const float* __restrict__ filt_col, const float* __restrict__ filt_row) {
    __shared__ SMem smem;
    float hr[8], wr[8], hc[8], wc[8];
    load_filt(filt_row, hr, wr);
    load_filt(filt_col, hc, wc);
    inv_tile(smem.i, flatl, a, astride, sc, outp, ostride, hr, wr, hc, wc,
             blockIdx.y * 64, blockIdx.x * 64, threadIdx.x);
}

// ---- fused small-level core: fwd 3..5 (+thr) and inv 5..3, 64 WGs, plain launch.
// Phases p=0..5 -> lev 3,4,5 fwd then 5,4,3 inv. done[p] at bar[p*32].
// Static tile assignment (t = bid, bid+64, ...); gates wait on done counts
// (work-based, deadlock-free under any residency).
__global__ __launch_bounds__(256) void core_small(
    const float* __restrict__ scal, const float* __restrict__ ap,
    const float* __restrict__ bpp, const float* __restrict__ bmp,
    float* __restrict__ out, float* __restrict__ ws, unsigned* __restrict__ bar) {
    __shared__ SMem smem;
    const int tid = threadIdx.x, bid = blockIdx.x, nb = gridDim.x;
    const float alpha = *ap, bp = *bpp, bm = *bmp;
    const int N = 4096;
    float* flat = out + 16777216;
    const size_t Aoff[7]    = {0, 0, 4194304, 5242880, 5505024, 5570560, 5586944};
    const size_t flatOff[6] = {0, 12582912, 15728640, 16515072, 16711680, 16760832};
    const size_t finalOff = 16773120;
    float* P0 = ws + 5591040;
    float* P1 = ws + 5591040 + 4194304;

    const float* a_in = flat + finalOff;
    for (int p = 0; p < 6; ++p) {
        const int lev = (p < 3) ? (3 + p) : (8 - p);   // 3,4,5,5,4,3
        const int nt  = N >> (lev + 6);                // tiles/side (fwd & inv)
        const int Np  = nt * nt;

        // ---- gate: wait for all tiles of phase p-1 (relaxed poll + one acquire)
        if (p > 0) {
            const int pl  = (p - 1 < 3) ? (2 + p) : (9 - p);
            const int pnt = N >> (pl + 6);
            const unsigned tgt = (unsigned)(pnt * pnt);
            if (tid == 0) {
                while (__hip_atomic_load(&bar[(p - 1) * 32], __ATOMIC_RELAXED,
                                         __HIP_MEMORY_SCOPE_AGENT) < tgt) {
                    __builtin_amdgcn_s_sleep(2);
                }
            }
            __syncthreads();
            __builtin_amdgcn_fence(__ATOMIC_ACQUIRE, "agent");
        }

        float hr[8], wr[8], hc[8], wc[8];
        load_filt(scal + lev * 8, hr, wr);
        load_filt(scal + (lev + 1) * 8, hc, wc);
        unsigned cnt = 0;

        if (p < 3) {
            const int s = N >> lev, sh = s >> 1;
            const float* src = ws + Aoff[lev];
            float* All = (lev < 5) ? (ws + Aoff[lev + 1]) : (flat + finalOff);
            for (int t = bid; t < Np; t += nb) {
                if (cnt) __syncthreads();
                fwd_tile(smem.f, src, s, sh, flat + flatOff[lev], All, lev == 5,
                         hr, wr, hc, wc, alpha, bp, bm,
                         (t / nt) * 32, (t % nt) * 32, tid);
                ++cnt;
            }
        } else {
            const int sc = N >> (lev + 1), r = 2 * sc;
            float* outp = (lev & 1) ? P1 : P0;
            for (int t = bid; t < Np; t += nb) {
                if (cnt) __syncthreads();
                inv_tile(smem.i, flat + flatOff[lev], a_in, sc, sc, outp, r,
                         hr, wr, hc, wc, (t / nt) * 64, (t % nt) * 64, tid);
                ++cnt;
            }
            a_in = outp;  // uniform across block
        }

        // ---- signal: release fence, then count our tiles
        __syncthreads();
        if (tid == 0 && cnt) {
            __threadfence();
            atomicAdd(&bar[p * 32], cnt);
        }
    }
}

extern "C" void kernel_launch(void* const* d_in, const int* in_sizes, int n_in,
                              void* d_out, int out_size, void* d_ws, size_t ws_size,
                              hipStream_t stream) {
    const float* x    = (const float*)d_in[0];
    const float* scal = (const float*)d_in[1];  // 12 x 8
    const float* ap   = (const float*)d_in[2];
    const float* bp   = (const float*)d_in[3];
    const float* bm   = (const float*)d_in[4];
    float* out = (float*)d_out;
    float* ws  = (float*)d_ws;

    const int N = 4096;
    float* recon = out;
    float* flat  = out + 16777216;
    static const size_t Aoff[7]    = {0, 0, 4194304, 5242880, 5505024, 5570560, 5586944};
    static const size_t flatOff[6] = {0, 12582912, 15728640, 16515072, 16711680, 16760832};
    float* P0 = ws + 5591040;
    float* P1 = ws + 5591040 + 4194304;
    unsigned* bar = (unsigned*)(ws + 14680064);  // past all live ws data

    dim3 blk(256);

    // ---------------- Forward big levels 0..2 ----------------
    const float* src = x;
    for (int lev = 0; lev < 3; ++lev) {
        int s = N >> lev, sh = s >> 1;
        dim3 g(sh / 32, sh / 32);
        fwd_fused<<<g, blk, 0, stream>>>(src, s, sh, flat + flatOff[lev],
                                         ws + Aoff[lev + 1],
                                         scal + lev * 8, scal + (lev + 1) * 8,
                                         ap, bp, bm,
                                         (lev == 2) ? bar : (unsigned*)nullptr);
        src = ws + Aoff[lev + 1];
    }

    // ---------------- Fused small levels (fwd 3..5, thr, inv 5..3) ----------------
    core_small<<<dim3(CORE_WGS), blk, 0, stream>>>(scal, ap, bp, bm, out, ws, bar);

    // ---------------- Inverse big levels 2..0 ----------------
    const float* a_in = P1;  // inv lev3 (in core) wrote P1
    for (int lev = 2; lev >= 0; --lev) {
        int sc = N >> (lev + 1), r = 2 * sc;
        float* outp = (lev == 0) ? recon : ((lev & 1) ? P1 : P0);
        dim3 g(r / 64, r / 64);
        inv_fused<<<g, blk, 0, stream>>>(flat + flatOff[lev], a_in, sc,
                                         sc, outp, r,
                                         scal + (lev + 1) * 8, scal + lev * 8);
        a_in = outp;
    }
}

// Round 7
// 287.673 us; speedup vs baseline: 4.8795x; 1.1165x over previous
//
#include <hip/hip_runtime.h>

// 6-level 2D DB4 wavelet (forward -> soft threshold -> inverse), N=4096 fp32.
// R9: shorten per-block critical path + double occupancy. 12 plain launches
// (R8 proved launch boundaries are ~free; in-kernel gates/coop sync are not).
//   - fwd: row filter reads its 16-float window DIRECTLY from global (4x float4,
//     L1 dedups overlap) -> no xs LDS stage, one less __syncthreads.
//     LDS 40.3 -> 20.2 KB.
//   - inv: col inverse reads its 6-row windows DIRECTLY from global (lane-
//     consecutive cols = coalesced) -> no coeff LDS stage, one less sync.
//     LDS 39.2 -> 18.4 KB.
//   - filters kept h-only (signs inlined), stage-B split into D-pass/A-pass ->
//     <=64 VGPR; __launch_bounds__(256,8) => 8 blocks/CU (was 4).
//   - thr folded into fwd5 (proven R5/R8).
//
// d_out layout: [0 .. 16777216) reconstruction, [16777216 .. 33554432) flat coeffs.
// Flat per level: row i = [hh_i | hl_i | lh_i], row stride 3*sc; final thr(approx)
// (64x64) at the tail.
// ws layout (floats): A1..A6 [0 .. 5591040) | P0 (4194304) | P1 (4194304).

__device__ __forceinline__ float thrf(float t, float alpha, float bp, float bm) {
    float s1 = 1.0f / (1.0f + __expf(-alpha * (t - bp)));
    float s2 = 1.0f / (1.0f + __expf( alpha * (t + bm)));
    return t * (s1 + s2);
}

__device__ __forceinline__ void load_h(const float* __restrict__ filt,
                                       float (&h)[8]) {
#pragma unroll
    for (int k = 0; k < 8; ++k) h[k] = filt[k];
}

struct SMemF { float Ds[70][36]; float As[70][36]; };  // 20160 B
struct SMemI { float Hs[64][36]; float Ls[64][36]; };  // 18432 B

// Forward tile: X (s x s) -> thresholded hh|hl|lh into flat (stride 3*sh)
// + ll into All (stride sh; thresholded too when thr_ll).
// h = row filter taps, g = col filter taps. Wavelet signs are inlined:
//   wr[7-u] = (u even ? -h[u] : h[u]);  hr[7-u] = h[7-u]   (verified vs R3).
__device__ __forceinline__ void fwd_tile(
    SMemF& sm, const float* __restrict__ X, int s, int sh,
    float* __restrict__ flat, float* __restrict__ All, bool thr_ll,
    const float (&h)[8], const float (&g)[8],
    float alpha, float bp, float bm, int i0, int j0, int tid) {
    const int smk = s - 1;
    // stage A: row filter straight from global (window = 4 aligned float4;
    // base 2*j0-8+8q is a multiple of 8, s a multiple of 4 -> no wrap straddle).
    for (int idx = tid; idx < 70 * 8; idx += 256) {
        int rr = idx >> 3, q = idx & 7;
        int gr = (2 * i0 - 7 + rr) & smk;
        const float* xrow = X + (size_t)gr * s;
        int cbase = 2 * j0 - 8 + 8 * q;
        float wv[16];
#pragma unroll
        for (int m = 0; m < 4; ++m) {
            float4 t = *(const float4*)&xrow[(cbase + 4 * m) & smk];
            wv[4 * m + 0] = t.x; wv[4 * m + 1] = t.y;
            wv[4 * m + 2] = t.z; wv[4 * m + 3] = t.w;
        }
        float d[4], a[4];
#pragma unroll
        for (int e = 0; e < 4; ++e) {
            float dd = 0.f, aa = 0.f;
#pragma unroll
            for (int u = 0; u < 8; ++u) {
                float v = wv[2 * e + 1 + u];
                aa += h[7 - u] * v;
                dd += (u & 1) ? h[u] * v : -h[u] * v;
            }
            d[e] = dd; a[e] = aa;
        }
        *(float4*)&sm.Ds[rr][4 * q] = make_float4(d[0], d[1], d[2], d[3]);
        *(float4*)&sm.As[rr][4 * q] = make_float4(a[0], a[1], a[2], a[3]);
    }
    __syncthreads();
    // stage B: col filter from LDS; D-pass then A-pass (register-lean).
    const int j = tid & 31, iq = tid >> 5;
    {
        float Dw[14];
#pragma unroll
        for (int t = 0; t < 14; ++t) Dw[t] = sm.Ds[8 * iq + t][j];
#pragma unroll
        for (int e = 0; e < 4; ++e) {
            float hh = 0.f, hl = 0.f;
#pragma unroll
            for (int u = 0; u < 8; ++u) {
                float dv = Dw[2 * e + u];
                hl += g[7 - u] * dv;
                hh += (u & 1) ? g[u] * dv : -g[u] * dv;
            }
            int row = i0 + 4 * iq + e;
            size_t ro = (size_t)row * (3 * sh) + (j0 + j);
            flat[ro]      = thrf(hh, alpha, bp, bm);
            flat[ro + sh] = thrf(hl, alpha, bp, bm);
        }
    }
    {
        float Aw[14];
#pragma unroll
        for (int t = 0; t < 14; ++t) Aw[t] = sm.As[8 * iq + t][j];
#pragma unroll
        for (int e = 0; e < 4; ++e) {
            float lh = 0.f, ll = 0.f;
#pragma unroll
            for (int u = 0; u < 8; ++u) {
                float av = Aw[2 * e + u];
                ll += g[7 - u] * av;
                lh += (u & 1) ? g[u] * av : -g[u] * av;
            }
            int row = i0 + 4 * iq + e;
            size_t ro = (size_t)row * (3 * sh) + (j0 + j);
            flat[ro + 2 * sh] = thrf(lh, alpha, bp, bm);
            All[(size_t)row * sh + (j0 + j)] =
                thr_ll ? thrf(ll, alpha, bp, bm) : ll;
        }
    }
}

// Inverse tile: hh|hl|lh (stride 3*sc) + a (stride astride) -> 64x64 out tile.
// g = col filter taps (stage A), h = row filter taps (stage B). Sign mapping:
//   wc[2t] = g[7-2t], wc[2t+1] = -g[6-2t]  (verified vs R3).
__device__ __forceinline__ void inv_tile(
    SMemI& sm, const float* __restrict__ flatl, const float* __restrict__ a,
    int astride, int sc, float* __restrict__ outp, int ostride,
    const float (&h)[8], const float (&g)[8],
    int i0, int m0, int tid) {
    const int mm = sc - 1;
    const int r0 = i0 >> 1, c0 = m0 >> 1;
    const int ds = 3 * sc;
    // stage A: col inverse straight from global (lane-consecutive cols ->
    // coalesced rows; block working set ~21 KB -> L1-resident).
    for (int idx = tid; idx < 16 * 36; idx += 256) {
        int q = idx / 36, jj = idx - q * 36;
        int gc = (c0 + jj) & mm;
        {   // H from (hh, hl)
            float hv[6], lv[6];
#pragma unroll
            for (int d = 0; d < 6; ++d) {
                size_t o = (size_t)((r0 + 2 * q + d) & mm) * ds + gc;
                hv[d] = flatl[o];
                lv[d] = flatl[o + sc];
            }
            float H0 = 0.f, H1 = 0.f, H2 = 0.f, H3 = 0.f;
#pragma unroll
            for (int t = 0; t < 4; ++t) {
                float we = g[7 - 2 * t], wo = -g[6 - 2 * t];
                float he = g[2 * t],     ho = g[2 * t + 1];
                H0 += we * hv[t]     + he * lv[t];
                H1 += wo * hv[t + 1] + ho * lv[t + 1];
                H2 += we * hv[t + 1] + he * lv[t + 1];
                H3 += wo * hv[t + 2] + ho * lv[t + 2];
            }
            sm.Hs[4 * q + 0][jj] = H0; sm.Hs[4 * q + 1][jj] = H1;
            sm.Hs[4 * q + 2][jj] = H2; sm.Hs[4 * q + 3][jj] = H3;
        }
        {   // L from (lh, a)
            float gv[6], av[6];
#pragma unroll
            for (int d = 0; d < 6; ++d) {
                int grr = (r0 + 2 * q + d) & mm;
                gv[d] = flatl[(size_t)grr * ds + 2 * sc + gc];
                av[d] = a[(size_t)grr * astride + gc];
            }
            float L0 = 0.f, L1 = 0.f, L2 = 0.f, L3 = 0.f;
#pragma unroll
            for (int t = 0; t < 4; ++t) {
                float we = g[7 - 2 * t], wo = -g[6 - 2 * t];
                float he = g[2 * t],     ho = g[2 * t + 1];
                L0 += we * gv[t]     + he * av[t];
                L1 += wo * gv[t + 1] + ho * av[t + 1];
                L2 += we * gv[t + 1] + he * av[t + 1];
                L3 += wo * gv[t + 2] + ho * av[t + 2];
            }
            sm.Ls[4 * q + 0][jj] = L0; sm.Ls[4 * q + 1][jj] = L1;
            sm.Ls[4 * q + 2][jj] = L2; sm.Ls[4 * q + 3][jj] = L3;
        }
    }
    __syncthreads();
    // stage B: row inverse from LDS, float4 store.
    for (int idx = tid; idx < 64 * 16; idx += 256) {
        int i = idx >> 4, p = idx & 15;
        const float2* hp = (const float2*)&sm.Hs[i][2 * p];
        const float2* lp = (const float2*)&sm.Ls[i][2 * p];
        float2 hA = hp[0], hB = hp[1], hC = hp[2];
        float2 lA = lp[0], lB = lp[1], lC = lp[2];
        float Hw[6] = {hA.x, hA.y, hB.x, hB.y, hC.x, hC.y};
        float Lw[6] = {lA.x, lA.y, lB.x, lB.y, lC.x, lC.y};
        float o0 = 0.f, o1 = 0.f, o2 = 0.f, o3 = 0.f;
#pragma unroll
        for (int t = 0; t < 4; ++t) {
            float we = h[7 - 2 * t], wo = -h[6 - 2 * t];
            float he = h[2 * t],     ho = h[2 * t + 1];
            o0 += we * Hw[t]     + he * Lw[t];
            o1 += wo * Hw[t + 1] + ho * Lw[t + 1];
            o2 += we * Hw[t + 1] + he * Lw[t + 1];
            o3 += wo * Hw[t + 2] + ho * Lw[t + 2];
        }
        *(float4*)&outp[(size_t)(i0 + i) * ostride + (m0 + 4 * p)] =
            make_float4(o0, o1, o2, o3);
    }
}

__global__ __launch_bounds__(256, 8) void fwd_fused(
    const float* __restrict__ X, int s, int sh,
    float* __restrict__ flat, float* __restrict__ All, int thr_ll,
    const float* __restrict__ filt_row, const float* __restrict__ filt_col,
    const float* __restrict__ ap, const float* __restrict__ bpp,
    const float* __restrict__ bmp) {
    __shared__ SMemF smem;
    float h[8], g[8];
    load_h(filt_row, h);
    load_h(filt_col, g);
    const float alpha = *ap, bp = *bpp, bm = *bmp;
    fwd_tile(smem, X, s, sh, flat, All, thr_ll != 0, h, g,
             alpha, bp, bm, blockIdx.y * 32, blockIdx.x * 32, threadIdx.x);
}

__global__ __launch_bounds__(256, 8) void inv_fused(
    const float* __restrict__ flatl, const float* __restrict__ a, int astride,
    int sc, float* __restrict__ outp, int ostride,
    const float* __restrict__ filt_col, const float* __restrict__ filt_row) {
    __shared__ SMemI smem;
    float h[8], g[8];
    load_h(filt_row, h);
    load_h(filt_col, g);
    inv_tile(smem, flatl, a, astride, sc, outp, ostride, h, g,
             blockIdx.y * 64, blockIdx.x * 64, threadIdx.x);
}

extern "C" void kernel_launch(void* const* d_in, const int* in_sizes, int n_in,
                              void* d_out, int out_size, void* d_ws, size_t ws_size,
                              hipStream_t stream) {
    const float* x    = (const float*)d_in[0];
    const float* scal = (const float*)d_in[1];  // 12 x 8
    const float* ap   = (const float*)d_in[2];
    const float* bp   = (const float*)d_in[3];
    const float* bm   = (const float*)d_in[4];
    float* out = (float*)d_out;
    float* ws  = (float*)d_ws;

    const int N = 4096;
    float* recon = out;
    float* flat  = out + 16777216;
    static const size_t Aoff[7]    = {0, 0, 4194304, 5242880, 5505024, 5570560, 5586944};
    static const size_t flatOff[6] = {0, 12582912, 15728640, 16515072, 16711680, 16760832};
    const size_t finalOff = 16773120;
    float* P0 = ws + 5591040;
    float* P1 = ws + 5591040 + 4194304;

    dim3 blk(256);

    // ---------------- Forward levels 0..5 (thr folded into lev 5) ----------------
    const float* src = x;
    for (int lev = 0; lev < 6; ++lev) {
        int s = N >> lev, sh = s >> 1;
        dim3 g(sh / 32, sh / 32);
        float* All = (lev < 5) ? (ws + Aoff[lev + 1]) : (flat + finalOff);
        fwd_fused<<<g, blk, 0, stream>>>(src, s, sh, flat + flatOff[lev], All,
                                         (lev == 5) ? 1 : 0,
                                         scal + lev * 8, scal + (lev + 1) * 8,
                                         ap, bp, bm);
        src = ws + Aoff[lev + 1];
    }

    // ---------------- Inverse levels 5..0 ----------------
    const float* a_in = flat + finalOff;
    for (int lev = 5; lev >= 0; --lev) {
        int sc = N >> (lev + 1), r = 2 * sc;
        float* outp = (lev == 0) ? recon : ((lev & 1) ? P1 : P0);
        dim3 g(r / 64, r / 64);
        inv_fused<<<g, blk, 0, stream>>>(flat + flatOff[lev], a_in, sc,
                                         sc, outp, r,
                                         scal + (lev + 1) * 8, scal + lev * 8);
        a_in = outp;
    }
}